// Round 3
// baseline (740.800 us; speedup 1.0000x reference)
//
#include <hip/hip_runtime.h>
#include <hip/hip_bf16.h>
#include <math.h>

// align = einsum('bsh,bh->bs', enc, states)/512; w = softmax(align, axis=1);
// ctx = einsum('bsh,bs->bh', enc, w). B=32, S=8192, H=512, fp32.
// enc = 512 MiB > L3 -> single fused pass, no online-max (|align| < ~0.3 in fp32).
// This revision targets memory-level parallelism: 2-stage register pipeline
// (prefetch next 4 rows while reducing current 4), 4-wave blocks, full-wave rows.

#define BB 32
#define SS 8192
#define HH 512
#define CPB 128               // blocks per batch (4096 total)
#define RPW 16                // rows per wave; 4 waves/block -> 64 rows/block
#define NP 512                // partials per batch = CPB*4

__global__ __launch_bounds__(256, 4) void attn_pass1(
    const float* __restrict__ states, const float* __restrict__ enc,
    float* __restrict__ align, float* __restrict__ pl, float* __restrict__ pC)
{
    const int blk  = blockIdx.x;
    const int b    = blk >> 7;
    const int c    = blk & 127;
    const int lane = threadIdx.x & 63;
    const int wv   = threadIdx.x >> 6;
    const int p    = (c << 2) | wv;          // partial index, 0..511

    // lane owns h in [4*lane, 4*lane+4) and [256+4*lane, 256+4*lane+4)
    const float4* st4 = (const float4*)(states + (size_t)b * HH);
    const float4 sh0 = st4[lane];
    const float4 sh1 = st4[lane + 64];

    // this wave's 16 rows, each row = 128 float4s
    const float4* rp = (const float4*)(enc + ((size_t)b * SS + (size_t)p * RPW) * HH);

    float4 ctx0 = make_float4(0.f,0.f,0.f,0.f);
    float4 ctx1 = make_float4(0.f,0.f,0.f,0.f);
    float  lsum = 0.0f, my_a = 0.0f;

    float4 cur0[4], cur1[4], nxt0[4], nxt1[4];
    #pragma unroll
    for (int r = 0; r < 4; ++r) {
        cur0[r] = rp[r * 128 + lane];
        cur1[r] = rp[r * 128 + 64 + lane];
    }

    #pragma unroll
    for (int it = 0; it < 4; ++it) {
        // prefetch next 4 rows while current 4 are being reduced
        if (it < 3) {
            #pragma unroll
            for (int r = 0; r < 4; ++r) {
                nxt0[r] = rp[(it * 4 + 4 + r) * 128 + lane];
                nxt1[r] = rp[(it * 4 + 4 + r) * 128 + 64 + lane];
            }
        }
        #pragma unroll
        for (int r = 0; r < 4; ++r) {
            const float4 e0 = cur0[r], e1 = cur1[r];
            float d = e0.x*sh0.x + e0.y*sh0.y + e0.z*sh0.z + e0.w*sh0.w
                    + e1.x*sh1.x + e1.y*sh1.y + e1.z*sh1.z + e1.w*sh1.w;
            #pragma unroll
            for (int mask = 1; mask < 64; mask <<= 1)
                d += __shfl_xor(d, mask, 64);
            const float a = d * (1.0f / 512.0f);
            const int row = it * 4 + r;
            if (lane == row) my_a = a;       // lane row keeps align of row 'row'
            const float pr = __expf(a);
            lsum += pr;                       // identical across all 64 lanes
            ctx0.x = fmaf(pr, e0.x, ctx0.x);
            ctx0.y = fmaf(pr, e0.y, ctx0.y);
            ctx0.z = fmaf(pr, e0.z, ctx0.z);
            ctx0.w = fmaf(pr, e0.w, ctx0.w);
            ctx1.x = fmaf(pr, e1.x, ctx1.x);
            ctx1.y = fmaf(pr, e1.y, ctx1.y);
            ctx1.z = fmaf(pr, e1.z, ctx1.z);
            ctx1.w = fmaf(pr, e1.w, ctx1.w);
        }
        #pragma unroll
        for (int r = 0; r < 4; ++r) { cur0[r] = nxt0[r]; cur1[r] = nxt1[r]; }
    }

    if (lane < RPW) align[(size_t)b * SS + (size_t)p * RPW + lane] = my_a;
    if (lane == 0)  pl[b * NP + p] = lsum;
    float4* Cp = (float4*)(pC + ((size_t)b * NP + p) * HH);
    Cp[lane]      = ctx0;
    Cp[lane + 64] = ctx1;
}

// pass2: grid = BB*10. slice 0-1: context halves; slice 2-9: weights chunks.
__global__ __launch_bounds__(256) void attn_pass2(
    const float* __restrict__ align, const float* __restrict__ pl,
    const float* __restrict__ pC, float* __restrict__ out_ctx,
    float* __restrict__ out_w)
{
    const int b     = blockIdx.x / 10;
    const int slice = blockIdx.x % 10;
    const int t     = threadIdx.x;

    __shared__ float sred[4];
    float v = pl[b * NP + t] + pl[b * NP + 256 + t];
    #pragma unroll
    for (int mask = 1; mask < 64; mask <<= 1)
        v += __shfl_xor(v, mask, 64);
    if ((t & 63) == 0) sred[t >> 6] = v;
    __syncthreads();
    const float invL = 1.0f / (sred[0] + sred[1] + sred[2] + sred[3]);

    if (slice < 2) {
        const int h = (slice << 8) + t;
        const float* Cb = pC + (size_t)b * NP * HH + h;
        float a0 = 0.f, a1 = 0.f, a2 = 0.f, a3 = 0.f;
        #pragma unroll 4
        for (int pp = 0; pp < NP; pp += 4) {
            a0 += Cb[(size_t)(pp + 0) * HH];
            a1 += Cb[(size_t)(pp + 1) * HH];
            a2 += Cb[(size_t)(pp + 2) * HH];
            a3 += Cb[(size_t)(pp + 3) * HH];
        }
        out_ctx[b * HH + h] = (a0 + a1 + a2 + a3) * invL;
    } else {
        const int s0 = (slice - 2) * 1024;
        const float* al = align + (size_t)b * SS + s0;
        float*       ow = out_w + (size_t)b * SS + s0;
        #pragma unroll
        for (int i = 0; i < 4; ++i)
            ow[t + i * 256] = __expf(al[t + i * 256]) * invL;
    }
}

extern "C" void kernel_launch(void* const* d_in, const int* in_sizes, int n_in,
                              void* d_out, int out_size, void* d_ws, size_t ws_size,
                              hipStream_t stream) {
    const float* states = (const float*)d_in[0];   // (32, 512)
    const float* enc    = (const float*)d_in[1];   // (32, 8192, 512)

    float* out_ctx = (float*)d_out;                    // 32*512
    float* out_w   = (float*)d_out + (size_t)BB * HH;  // 32*8192

    // ws: align[BB*SS] | pl[BB*NP] | pC[BB*NP*HH]  (~33 MB)
    float* ws_align = (float*)d_ws;
    float* ws_pl    = ws_align + (size_t)BB * SS;
    float* ws_pC    = ws_pl    + (size_t)BB * NP;

    attn_pass1<<<BB * CPB, 256, 0, stream>>>(states, enc, ws_align, ws_pl, ws_pC);
    attn_pass2<<<BB * 10, 256, 0, stream>>>(ws_align, ws_pl, ws_pC, out_ctx, out_w);
}